// Round 7
// baseline (917.471 us; speedup 1.0000x reference)
//
#include <hip/hip_runtime.h>
#include <math.h>

#define HH 512
#define NHEADS 4
#define HD 128
#define HALF 64
#define FFND 2048
#define BB 4
#define SS 2048
#define NLAYERS 3
#define ROWS (BB*SS)
#define EPSF 1e-5f
#define QKVGW 2048

typedef float f32x4 __attribute__((ext_vector_type(4)));
typedef float f32x16 __attribute__((ext_vector_type(16)));
typedef __bf16 bf16x8 __attribute__((ext_vector_type(8)));
typedef unsigned u32x2 __attribute__((ext_vector_type(2)));

__device__ __forceinline__ unsigned short f2bf(float f) {
    union { float f; unsigned u; } v; v.f = f;
    unsigned r = (v.u + 0x7FFFu + ((v.u >> 16) & 1u)) >> 16;
    return (unsigned short)r;
}
__device__ __forceinline__ float bf2f(unsigned short h) {
    union { unsigned u; float f; } v; v.u = ((unsigned)h) << 16;
    return v.f;
}
__device__ __forceinline__ void gl16(const void* g, void* l) {
    __builtin_amdgcn_global_load_lds((const __attribute__((address_space(1))) void*)g,
                                     (__attribute__((address_space(3))) void*)l, 16, 0, 0);
}
__device__ __forceinline__ bf16x8 ld8(const void* p) { return *(const bf16x8*)p; }
__device__ __forceinline__ unsigned laddr(void* p) {
    return (unsigned)(size_t)(__attribute__((address_space(3))) char*)p;
}
__device__ __forceinline__ u32x2 tr8(unsigned a) {
    u32x2 r;
    asm volatile("ds_read_b64_tr_b16 %0, %1" : "=v"(r) : "v"(a));
    return r;
}

// ---------------------------------------------------------------- xpos tables
__global__ void k_tables(float* __restrict__ cq, float* __restrict__ sq,
                         float* __restrict__ ck, float* __restrict__ sk) {
    int i = threadIdx.x;
    int s = blockIdx.x;
    float si   = ((float)i + 0.4f * (float)HD) / (1.4f * (float)HD);
    float scale = powf(si, (float)s / 512.0f);
    float invf = powf(10000.0f, -((float)i) / (float)HALF);
    float ang  = (float)s * invf;
    float c = cosf(ang), sn = sinf(ang);
    int idx = s * HALF + i;
    cq[idx] = c * scale;   sq[idx] = sn * scale;
    float is = 1.0f / scale;
    ck[idx] = c * is;      sk[idx] = sn * is;
}

// ---------------------------------------------------------------- weight transpose+cast
__global__ __launch_bounds__(256) void k_wt(const float* __restrict__ src, unsigned short* __restrict__ dst,
                                            int K, int N, int zn, size_t sL, size_t sZ) {
    __shared__ float T[32][33];
    int n0 = blockIdx.x * 32, k0 = blockIdx.y * 32;
    int z = blockIdx.z;
    src += (size_t)z * (size_t)K * N;
    dst += (size_t)(z / zn) * sL + (size_t)(z % zn) * sZ;
    int tx = threadIdx.x & 31, ty = threadIdx.x >> 5;
    #pragma unroll
    for (int i = 0; i < 4; ++i) {
        int r = ty + i * 8;
        T[r][tx] = src[(size_t)(k0 + r) * N + n0 + tx];
    }
    __syncthreads();
    #pragma unroll
    for (int i = 0; i < 4; ++i) {
        int r = ty + i * 8;
        dst[(size_t)(n0 + r) * K + k0 + tx] = f2bf(T[tx][r]);
    }
}

// ---------------------------------------------------------------- layernorm fp32 -> bf16
__global__ __launch_bounds__(256) void k_ln(const float* __restrict__ x, const float* __restrict__ w,
                                            const float* __restrict__ b, unsigned short* __restrict__ y) {
    int lane = threadIdx.x & 63;
    size_t row = (size_t)blockIdx.x * 4 + (threadIdx.x >> 6);
    const float4* xr = (const float4*)(x + row * HH);
    float4 v0 = xr[lane * 2];
    float4 v1 = xr[lane * 2 + 1];
    float s  = v0.x + v0.y + v0.z + v0.w + v1.x + v1.y + v1.z + v1.w;
    float ss = v0.x*v0.x + v0.y*v0.y + v0.z*v0.z + v0.w*v0.w
             + v1.x*v1.x + v1.y*v1.y + v1.z*v1.z + v1.w*v1.w;
    for (int off = 32; off > 0; off >>= 1) {
        s  += __shfl_xor(s, off);
        ss += __shfl_xor(ss, off);
    }
    float m   = s * (1.0f / HH);
    float var = ss * (1.0f / HH) - m * m;
    float inv = rsqrtf(var + EPSF);
    int h0 = lane * 8;
    float4 wa = *(const float4*)(w + h0);
    float4 wb = *(const float4*)(w + h0 + 4);
    float4 ba = *(const float4*)(b + h0);
    float4 bb2 = *(const float4*)(b + h0 + 4);
    uint4 pk;
    pk.x = f2bf((v0.x - m) * inv * wa.x + ba.x) | ((unsigned)f2bf((v0.y - m) * inv * wa.y + ba.y) << 16);
    pk.y = f2bf((v0.z - m) * inv * wa.z + ba.z) | ((unsigned)f2bf((v0.w - m) * inv * wa.w + ba.w) << 16);
    pk.z = f2bf((v1.x - m) * inv * wb.x + bb2.x) | ((unsigned)f2bf((v1.y - m) * inv * wb.y + bb2.y) << 16);
    pk.w = f2bf((v1.z - m) * inv * wb.z + bb2.z) | ((unsigned)f2bf((v1.w - m) * inv * wb.w + bb2.w) << 16);
    *(uint4*)(y + row * HH + h0) = pk;
}

// ---------------------------------------------------------------- xpos rotate Q,K inside QKVG
__global__ __launch_bounds__(256) void k_xpos(unsigned short* __restrict__ QG,
    const float* __restrict__ cq, const float* __restrict__ sq,
    const float* __restrict__ ck, const float* __restrict__ sk) {
    int row = blockIdx.x, p = threadIdx.x;
    int s = row & (SS - 1), n = p >> 6, i = p & 63;
    int ti = s * HALF + i;
    size_t qo = (size_t)row * QKVGW + n * HD + i * 2;
    unsigned qv = *(unsigned*)(QG + qo);
    float x1 = bf2f(qv & 0xffff), x2 = bf2f(qv >> 16);
    float c = cq[ti], sn = sq[ti];
    *(unsigned*)(QG + qo) = (unsigned)f2bf(x1 * c - x2 * sn) | ((unsigned)f2bf(x2 * c + x1 * sn) << 16);
    size_t ko = qo + 512;
    unsigned kv = *(unsigned*)(QG + ko);
    x1 = bf2f(kv & 0xffff); x2 = bf2f(kv >> 16);
    c = ck[ti]; sn = sk[ti];
    *(unsigned*)(QG + ko) = (unsigned)f2bf(x1 * c - x2 * sn) | ((unsigned)f2bf(x2 * c + x1 * sn) << 16);
}

// ---------------------------------------------------------------- chunk state: B_c[dk][dv] = sum_t g^(128-t) K[t][dk] V[t][dv]
// grid (16 chunks, 4 hn, 4 b), 4 waves. K,V staged subtiled [db8][tb32][4][16]; both operands via tr8.
__global__ __launch_bounds__(256, 2) void k_state(
    const unsigned short* __restrict__ QG, unsigned short* __restrict__ Bbuf) {
    __shared__ __align__(16) char sm[65536];
    const int tid = threadIdx.x;
    const int lane = tid & 63, wv = tid >> 6;
    const int l31 = lane & 31, g2 = lane >> 5;
    const int b4 = (lane >> 4) & 1;
    const int c = blockIdx.x, hn = blockIdx.y, b = blockIdx.z;
    const double la = -3.4657359027997265, lb = -6.238324625039508;
    const float gamma = (float)(1.0 - exp(la + (lb - la) * ((double)hn / 3.0)));
    const float l2g = log2f(gamma);
    const size_t rowbase = (size_t)b * SS + c * 128;
    const int kcol = 512 + hn * HD, vcol = 1024 + hn * HD;
    const char* Gp = (const char*)QG;
    #pragma unroll
    for (int c2 = 0; c2 < 8; ++c2) {
        int slot = c2 * 256 + tid;
        int sub = slot >> 3, w8 = slot & 7;
        int db = sub >> 5, tb = sub & 31;
        int tl = tb * 4 + (w8 >> 1);
        int d  = db * 16 + (w8 & 1) * 8;
        gl16(Gp + ((rowbase + tl) * QKVGW + kcol + d) * 2, sm + slot * 16);
        gl16(Gp + ((rowbase + tl) * QKVGW + vcol + d) * 2, sm + 32768 + slot * 16);
    }
    asm volatile("s_waitcnt vmcnt(0)" ::: "memory");
    __builtin_amdgcn_s_barrier();
    float sce[8];
    #pragma unroll
    for (int e = 0; e < 8; ++e) sce[e] = exp2f(l2g * (float)(128 - g2 * 8 - e));
    f32x16 acc[4];
    #pragma unroll
    for (int d = 0; d < 4; ++d)
        #pragma unroll
        for (int e = 0; e < 16; ++e) acc[d][e] = 0.0f;
    const unsigned kb = laddr(sm) + (wv * 2 + b4) * 4096 + g2 * 256 + (lane & 15) * 2;
    const unsigned vb = laddr(sm + 32768) + b4 * 4096 + g2 * 256 + (lane & 15) * 2;
    #pragma unroll
    for (int kc = 0; kc < 8; ++kc) {
        u32x2 ka = tr8(kb + kc * 512);
        u32x2 kb2 = tr8(kb + kc * 512 + 128);
        u32x2 vv[8];
        #pragma unroll
        for (int dblk = 0; dblk < 4; ++dblk) {
            vv[dblk * 2]     = tr8(vb + dblk * 8192 + kc * 512);
            vv[dblk * 2 + 1] = tr8(vb + dblk * 8192 + kc * 512 + 128);
        }
        asm volatile("s_waitcnt lgkmcnt(0)" ::: "memory");
        __builtin_amdgcn_sched_barrier(0);
        const float gkc = exp2f(l2g * (float)(-16 * kc));
        union { u32x2 u[2]; unsigned short s[8]; bf16x8 v; } af, ap;
        af.u[0] = ka; af.u[1] = kb2;
        #pragma unroll
        for (int e = 0; e < 8; ++e) ap.s[e] = f2bf(bf2f(af.s[e]) * (sce[e] * gkc));
        #pragma unroll
        for (int dblk = 0; dblk < 4; ++dblk) {
            union { u32x2 u[2]; bf16x8 v; } bv;
            bv.u[0] = vv[dblk * 2]; bv.u[1] = vv[dblk * 2 + 1];
            acc[dblk] = __builtin_amdgcn_mfma_f32_32x32x16_bf16(ap.v, bv.v, acc[dblk], 0, 0, 0);
        }
    }
    unsigned short* Bp = Bbuf + (((size_t)(b * 4 + hn) * 16 + c) * 16384);
    #pragma unroll
    for (int dblk = 0; dblk < 4; ++dblk)
        #pragma unroll
        for (int reg = 0; reg < 16; ++reg) {
            int row = (reg & 3) + 8 * (reg >> 2) + 4 * g2 + wv * 32;
            Bp[row * 128 + dblk * 32 + l31] = f2bf(acc[dblk][reg]);
        }
}

// ---------------------------------------------------------------- scan: A_c = g^128 * A_{c-1} + B_{c-1}, A_0 = 0
__global__ __launch_bounds__(256) void k_scan(const unsigned short* __restrict__ Bbuf,
                                              unsigned short* __restrict__ Abuf) {
    const int tid = threadIdx.x;
    const int rg = blockIdx.x, hn = blockIdx.y, b = blockIdx.z;
    const double la = -3.4657359027997265, lb = -6.238324625039508;
    const float gamma = (float)(1.0 - exp(la + (lb - la) * ((double)hn / 3.0)));
    const float gC = exp2f(log2f(gamma) * 128.0f);
    const size_t ubase = ((size_t)(b * 4 + hn) * 16) * 16384;
    const size_t off = (size_t)rg * 4096 + (size_t)tid * 16;
    float a[16];
    #pragma unroll
    for (int e = 0; e < 16; ++e) a[e] = 0.0f;
    for (int c = 1; c < 16; ++c) {
        const unsigned short* bp = Bbuf + ubase + (size_t)(c - 1) * 16384 + off;
        uint4 u0 = *(const uint4*)bp;
        uint4 u1 = *(const uint4*)(bp + 8);
        const unsigned short* up0 = (const unsigned short*)&u0;
        const unsigned short* up1 = (const unsigned short*)&u1;
        #pragma unroll
        for (int e = 0; e < 8; ++e) a[e] = gC * a[e] + bf2f(up0[e]);
        #pragma unroll
        for (int e = 0; e < 8; ++e) a[8 + e] = gC * a[8 + e] + bf2f(up1[e]);
        uint4 o0, o1;
        unsigned short* op0 = (unsigned short*)&o0;
        unsigned short* op1 = (unsigned short*)&o1;
        #pragma unroll
        for (int e = 0; e < 8; ++e) op0[e] = f2bf(a[e]);
        #pragma unroll
        for (int e = 0; e < 8; ++e) op1[e] = f2bf(a[8 + e]);
        unsigned short* ap2 = Abuf + ubase + (size_t)c * 16384 + off;
        *(uint4*)ap2 = o0;
        *(uint4*)(ap2 + 8) = o1;
    }
}

// ---------------------------------------------------------------- retention: cross (Q*A_c, row-scaled) + intra (2 t-tiles)
// grid (16 chunks, 4 hn, 4 b), 4 waves x 32 s-rows, 1 block/CU.
// LDS: K0 0, K1 16K, V0 32K, V1 48K (subtiled-64), A 64K (subtiled-128), P 96K..112K
__global__ __launch_bounds__(256, 1) void k_ret2(
    const unsigned short* __restrict__ QG, const unsigned short* __restrict__ Abuf,
    float* __restrict__ Y) {
    __shared__ __align__(16) char sm[114688];
    const int tid = threadIdx.x;
    const int lane = tid & 63, wv = tid >> 6;
    const int l31 = lane & 31, g2 = lane >> 5;
    const int b4 = (lane >> 4) & 1;
    const int c = blockIdx.x, hn = blockIdx.y, b = blockIdx.z;
    const int cC = c * 128;
    const double la = -3.4657359027997265, lb = -6.238324625039508;
    const float gamma = (float)(1.0 - exp(la + (lb - la) * ((double)hn / 3.0)));
    const float l2g = log2f(gamma);
    const size_t rowbase = (size_t)b * SS;
    const int qcol = hn * HD, kcol = 512 + hn * HD, vcol = 1024 + hn * HD;
    const char* Gp = (const char*)QG;
    const int srow = cC + wv * 32 + l31;
    bf16x8 qf[8];
    #pragma unroll
    for (int kc = 0; kc < 8; ++kc)
        qf[kc] = ld8(QG + (rowbase + srow) * QKVGW + qcol + kc * 16 + g2 * 8);
    // stage K0,K1 (row-major swizzled) + V0,V1 (subtiled-64)
    #pragma unroll
    for (int cc = 0; cc < 4; ++cc) {
        int chunk = wv * 4 + cc;
        int r = chunk * 4 + (lane >> 4);
        int w = ((lane & 15) * 16) ^ ((r & 15) << 4);
        gl16(Gp + ((rowbase + cC + r) * QKVGW + kcol) * 2 + w, sm + chunk * 1024);
        gl16(Gp + ((rowbase + cC + 64 + r) * QKVGW + kcol) * 2 + w, sm + 16384 + chunk * 1024);
        int slot = chunk * 64 + lane;
        int sub = slot >> 3, w8 = slot & 7;
        int db = sub >> 4, tb = sub & 15;
        int tl = tb * 4 + (w8 >> 1);
        int d  = db * 16 + (w8 & 1) * 8;
        gl16(Gp + ((rowbase + cC + tl) * QKVGW + vcol + d) * 2, sm + 32768 + slot * 16);
        gl16(Gp + ((rowbase + cC + 64 + tl) * QKVGW + vcol + d) * 2, sm + 49152 + slot * 16);
    }
    if (c > 0) {
        const char* Ap = (const char*)(Abuf + (((size_t)(b * 4 + hn) * 16 + c) * 16384));
        #pragma unroll
        for (int c2 = 0; c2 < 8; ++c2) {
            int slot = c2 * 256 + tid;
            int sub = slot >> 3, w8 = slot & 7;
            int db = sub >> 5, tb = sub & 31;
            int row = tb * 4 + (w8 >> 1);
            int d   = db * 16 + (w8 & 1) * 8;
            gl16(Ap + (row * 128 + d) * 2, sm + 65536 + slot * 16);
        }
    }
    asm volatile("s_waitcnt vmcnt(0)" ::: "memory");
    __builtin_amdgcn_s_barrier();
    f32x16 accy[4];
    #pragma unroll
    for (int d = 0; d < 4; ++d)
        #pragma unroll
        for (int e = 0; e < 16; ++e) accy[d][e] = 0.0f;
    // cross term: accy = Q * A_c, then scale rows by g^{s_local}
    if (c > 0) {
        const unsigned ab = laddr(sm + 65536) + b4 * 4096 + g2 * 256 + (lane & 15) * 2;
        #pragma unroll
        for (int dblk = 0; dblk < 4; ++dblk) {
            #pragma unroll
            for (int h = 0; h < 2; ++h) {
                u32x2 av[8];
                #pragma unroll
                for (int kc = 0; kc < 4; ++kc) {
                    unsigned a0 = ab + dblk * 8192 + (h * 4 + kc) * 512;
                    av[kc * 2] = tr8(a0);
                    av[kc * 2 + 1] = tr8(a0 + 128);
                }
                asm volatile("s_waitcnt lgkmcnt(0)" ::: "memory");
                __builtin_amdgcn_sched_barrier(0);
                #pragma unroll
                for (int kc = 0; kc < 4; ++kc) {
                    union { u32x2 u[2]; bf16x8 v; } bv;
                    bv.u[0] = av[kc * 2]; bv.u[1] = av[kc * 2 + 1];
                    accy[dblk] = __builtin_amdgcn_mfma_f32_32x32x16_bf16(qf[h * 4 + kc], bv.v, accy[dblk], 0, 0, 0);
                }
            }
        }
        #pragma unroll
        for (int reg = 0; reg < 16; ++reg) {
            float gsc = exp2f(l2g * (float)(wv * 32 + (reg & 3) + 8 * (reg >> 2) + 4 * g2));
            #pragma unroll
            for (int dblk = 0; dblk < 4; ++dblk) accy[dblk][reg] *= gsc;
        }
    }
    // intra tiles
    const int sloc = wv * 32 + l31;
    const int ssw = (sloc & 7) << 4;
    const int r15 = (l31 & 15) << 4;
    float gq[4], gj[4];
    #pragma unroll
    for (int q = 0; q < 4; ++q) { gq[q] = exp2f(-l2g * (8.0f * q)); gj[q] = exp2f(-l2g * (float)q); }
    const float gt32m = exp2f(-l2g * 32.0f);
    const int ntt = (wv >> 1) + 1;
    for (int tt = 0; tt < ntt; ++tt) {
        const int t0 = cC + tt * 64;
        const char* kb = sm + tt * 16384;
        f32x16 pacc0, pacc1;
        #pragma unroll
        for (int e = 0; e < 16; ++e) { pacc0[e] = 0.0f; pacc1[e] = 0.0f; }
        #pragma unroll
        for (int kc = 0; kc < 8; ++kc) {
            bf16x8 k0 = ld8(kb + l31 * 256 + ((kc * 32 + g2 * 16) ^ r15));
            bf16x8 k1 = ld8(kb + (32 + l31) * 256 + ((kc * 32 + g2 * 16) ^ r15));
            pacc0 = __builtin_amdgcn_mfma_f32_32x32x16_bf16(k0, qf[kc], pacc0, 0, 0, 0);
            pacc1 = __builtin_amdgcn_mfma_f32_32x32x16_bf16(k1, qf[kc], pacc1, 0, 0, 0);
        }
        const float G0 = exp2f(l2g * (float)(srow - t0 - g2 * 4));
        #pragma unroll
        for (int tb2 = 0; tb2 < 2; ++tb2) {
            const float gb = tb2 ? gt32m : 1.0f;
            #pragma unroll
            for (int q = 0; q < 4; ++q) {
                int tbase = t0 + tb2 * 32 + q * 8 + g2 * 4;
                float base = G0 * gb * gq[q];
                float p0 = (tb2 ? pacc1 : pacc0)[q * 4 + 0];
                float p1 = (tb2 ? pacc1 : pacc0)[q * 4 + 1];
                float p2 = (tb2 ? pacc1 : pacc0)[q * 4 + 2];
                float p3 = (tb2 ? pacc1 : pacc0)[q * 4 + 3];
                unsigned short u0 = f2bf((srow >= tbase + 0) ? p0 * base * gj[0] : 0.0f);
                unsigned short u1 = f2bf((srow >= tbase + 1) ? p1 * base * gj[1] : 0.0f);
                unsigned short u2 = f2bf((srow >= tbase + 2) ? p2 * base * gj[2] : 0.0f);
                unsigned short u3 = f2bf((srow >= tbase + 3) ? p3 * base * gj[3] : 0.0f);
                u32x2 pk2;
                pk2.x = (unsigned)u0 | ((unsigned)u1 << 16);
                pk2.y = (unsigned)u2 | ((unsigned)u3 << 16);
                *(u32x2*)(sm + 98304 + ((sloc * 128 + tb2 * 64 + q * 16 + g2 * 8) ^ ssw)) = pk2;
            }
        }
        bf16x8 pf[4];
        #pragma unroll
        for (int tc = 0; tc < 4; ++tc)
            pf[tc] = ld8(sm + 98304 + ((sloc * 128 + tc * 32 + g2 * 16) ^ ssw));
        const unsigned vbase = laddr(sm + 32768 + tt * 16384) + b4 * 2048 + g2 * 256 + (lane & 15) * 2;
        #pragma unroll
        for (int dblk = 0; dblk < 4; ++dblk) {
            u32x2 va[4], vb2[4];
            #pragma unroll
            for (int tc = 0; tc < 4; ++tc) {
                unsigned a0 = vbase + dblk * 4096 + tc * 512;
                va[tc] = tr8(a0);
                vb2[tc] = tr8(a0 + 128);
            }
            asm volatile("s_waitcnt lgkmcnt(0)" ::: "memory");
            __builtin_amdgcn_sched_barrier(0);
            #pragma unroll
            for (int tc = 0; tc < 4; ++tc) {
                union { u32x2 u[2]; bf16x8 v; } cvt;
                cvt.u[0] = va[tc]; cvt.u[1] = vb2[tc];
                accy[dblk] = __builtin_amdgcn_mfma_f32_32x32x16_bf16(pf[tc], cvt.v, accy[dblk], 0, 0, 0);
            }
        }
    }
    #pragma unroll
    for (int dblk = 0; dblk < 4; ++dblk)
        #pragma unroll
        for (int rg = 0; rg < 16; ++rg) {
            int sl2 = cC + wv * 32 + (rg & 3) + (rg >> 2) * 8 + g2 * 4;
            Y[(rowbase + sl2) * HH + hn * HD + dblk * 32 + l31] = accy[dblk][rg];
        }
}

// ---------------------------------------------------------------- groupnorm + silu gate
__global__ __launch_bounds__(256) void k_gate(
    const float* __restrict__ Yr, const unsigned short* __restrict__ QG,
    const float* __restrict__ gw, const float* __restrict__ gb,
    unsigned short* __restrict__ E) {
    int lane = threadIdx.x & 63;
    int grp  = blockIdx.x * 4 + (threadIdx.x >> 6);
    int row = grp >> 2, nh = grp & 3;
    size_t off = (size_t)row * HH + nh * HD + lane * 2;
    float2 v = *(const float2*)(Yr + off);
    float s = v.x + v.y, ss = v.x * v.x + v.y * v.y;
    for (int o = 32; o > 0; o >>= 1) {
        s  += __shfl_xor(s, o);
        ss += __shfl_xor(ss, o);
    }
    float m   = s * (1.0f / HD);
    float var = ss * (1.0f / HD) - m * m;
    float inv = rsqrtf(var + EPSF);
    int h = nh * HD + lane * 2;
    unsigned gv = *(const unsigned*)(QG + (size_t)row * QKVGW + 1536 + nh * HD + lane * 2);
    float g0 = bf2f(gv & 0xffff), g1 = bf2f(gv >> 16);
    float2 w2 = *(const float2*)(gw + h), b2 = *(const float2*)(gb + h);
    float yn0 = (v.x - m) * inv * w2.x + b2.x;
    float yn1 = (v.y - m) * inv * w2.y + b2.y;
    float e0v = g0 / (1.0f + expf(-g0)) * yn0;
    float e1v = g1 / (1.0f + expf(-g1)) * yn1;
    *(unsigned*)(E + off) = (unsigned)f2bf(e0v) | ((unsigned)f2bf(e1v) << 16);
}

// ---------------------------------------------------------------- bf16 MFMA GEMM 128x128x32 (BT weights)
// EPI: 0 none | 1 +bias,gelu | 2 +bias+res | 3 +res | 4 +bias+res, dual write (fp32 Cf + bf16 C2)
template<int EPI, int OUTBF>
__global__ __launch_bounds__(256) void k_mm(
    const unsigned short* __restrict__ A, const unsigned short* __restrict__ Bt,
    void* __restrict__ Cv, const float* __restrict__ bias, const float* __restrict__ Rs,
    int M, int N, int K, size_t aB, size_t bB, size_t cB,
    unsigned short* __restrict__ C2) {
    __shared__ __align__(16) char sm[16384];
    const int tid = threadIdx.x;
    const int lane = tid & 63, wid = tid >> 6;
    const int wr = wid >> 1, wc = wid & 1;
    const int lcol = lane & 15, lrow = lane >> 4;
    const size_t m0 = (size_t)blockIdx.x * 128, n0 = (size_t)blockIdx.y * 128;
    const char* Ab = (const char*)(A + (size_t)blockIdx.z * aB);
    const char* Bb = (const char*)(Bt + (size_t)blockIdx.z * bB);
    f32x4 acc[4][4];
    #pragma unroll
    for (int i = 0; i < 4; ++i)
        #pragma unroll
        for (int j = 0; j < 4; ++j) acc[i][j] = f32x4{0.f, 0.f, 0.f, 0.f};
    for (int k0 = 0; k0 < K; k0 += 32) {
        __syncthreads();
        #pragma unroll
        for (int c = 0; c < 2; ++c) {
            int chunk = wid * 2 + c;
            int r = chunk * 16 + (lane >> 2);
            int w = ((lane & 3) ^ (r & 3)) << 4;
            gl16(Ab + ((size_t)(m0 + r) * K + k0) * 2 + w, sm + chunk * 1024);
            gl16(Bb + ((size_t)(n0 + r) * K + k0) * 2 + w, sm + 8192 + chunk * 1024);
        }
        __syncthreads();
        bf16x8 af[4], bfr[4];
        #pragma unroll
        for (int m = 0; m < 4; ++m) {
            int r = wr * 64 + m * 16 + lcol;
            af[m] = ld8(sm + r * 64 + ((lrow * 16) ^ ((r & 3) << 4)));
        }
        #pragma unroll
        for (int n2 = 0; n2 < 4; ++n2) {
            int r = wc * 64 + n2 * 16 + lcol;
            bfr[n2] = ld8(sm + 8192 + r * 64 + ((lrow * 16) ^ ((r & 3) << 4)));
        }
        #pragma unroll
        for (int m = 0; m < 4; ++m)
            #pragma unroll
            for (int n2 = 0; n2 < 4; ++n2)
                acc[m][n2] = __builtin_amdgcn_mfma_f32_16x16x32_bf16(af[m], bfr[n2], acc[m][n2], 0, 0, 0);
    }
    float* Cf = (float*)Cv + (size_t)blockIdx.z * cB;
    unsigned short* Cb = (unsigned short*)Cv + (size_t)blockIdx.z * cB;
    const float* Rb = (EPI >= 2) ? (Rs + (size_t)blockIdx.z * cB) : nullptr;
    #pragma unroll
    for (int m = 0; m < 4; ++m) {
        #pragma unroll
        for (int n2 = 0; n2 < 4; ++n2) {
            size_t col = n0 + wc * 64 + n2 * 16 + lcol;
            float bc = (EPI == 1 || EPI == 2 || EPI == 4) ? bias[col] : 0.0f;
            #pragma unroll
            for (int j = 0; j < 4; ++j) {
                size_t row = m0 + wr * 64 + m * 16 + lrow * 4 + j;
                float v = acc[m][n2][j];
                if (EPI == 1) { v += bc; v = 0.5f * v * (1.0f + erff(v * 0.70710678118654752f)); }
                else if (EPI == 2 || EPI == 4) v += bc + Rb[row * N + col];
                else if (EPI == 3) v += Rb[row * N + col];
                if (EPI == 4) {
                    Cf[row * N + col] = v;
                    C2[row * N + col] = f2bf(v);
                } else if (OUTBF) Cb[row * N + col] = f2bf(v);
                else              Cf[row * N + col] = v;
            }
        }
    }
}

// ---------------------------------------------------------------- launch
extern "C" void kernel_launch(void* const* d_in, const int* in_sizes, int n_in,
                              void* d_out, int out_size, void* d_ws, size_t ws_size,
                              hipStream_t stream) {
    const float* X0  = (const float*)d_in[0];
    const float* WQ  = (const float*)d_in[1];
    const float* WK  = (const float*)d_in[2];
    const float* WV  = (const float*)d_in[3];
    const float* WG  = (const float*)d_in[4];
    const float* WO  = (const float*)d_in[5];
    const float* gnw = (const float*)d_in[6];
    const float* gnb = (const float*)d_in[7];
    const float* l1w = (const float*)d_in[8];
    const float* l1b = (const float*)d_in[9];
    const float* l2w = (const float*)d_in[10];
    const float* l2b = (const float*)d_in[11];
    const float* fw1 = (const float*)d_in[12];
    const float* fb1 = (const float*)d_in[13];
    const float* fw2 = (const float*)d_in[14];
    const float* fb2 = (const float*)d_in[15];
    float* outX = (float*)d_out;
    float* outG = outX + (size_t)ROWS * HH;

    char* wp = (char*)d_ws;
    auto take = [&](size_t bytes) { char* p = wp; wp += (bytes + 255) & ~(size_t)255; return p; };
    float* cq = (float*)take((size_t)SS * HALF * 4);
    float* sq = (float*)take((size_t)SS * HALF * 4);
    float* ck = (float*)take((size_t)SS * HALF * 4);
    float* sk = (float*)take((size_t)SS * HALF * 4);
    unsigned short* Wcat = (unsigned short*)take((size_t)NLAYERS * QKVGW * HH * 2);
    unsigned short* WOt = (unsigned short*)take((size_t)NLAYERS * HH * HH * 2);
    unsigned short* F1t = (unsigned short*)take((size_t)NLAYERS * HH * FFND * 2);
    unsigned short* F2t = (unsigned short*)take((size_t)NLAYERS * HH * FFND * 2);
    unsigned short* Xn  = (unsigned short*)take((size_t)ROWS * HH * 2);
    unsigned short* QKVG = (unsigned short*)take((size_t)ROWS * QKVGW * 2);
    unsigned short* Eb  = (unsigned short*)take((size_t)ROWS * HH * 2);
    float* Yr   = (float*)take((size_t)ROWS * HH * 4);
    float* Y2   = (float*)take((size_t)ROWS * HH * 4);
    float* Xbuf = (float*)take((size_t)ROWS * HH * 4);
    unsigned short* Hb = (unsigned short*)take((size_t)ROWS * FFND * 2);
    unsigned short* Xb = Xn;
    // chunk-state buffers alias Y2 (dead during retention; rewritten by WO GEMM afterwards)
    unsigned short* Bbuf = (unsigned short*)Y2;
    unsigned short* Abuf = Bbuf + (size_t)4194304;

    k_tables<<<SS, HALF, 0, stream>>>(cq, sq, ck, sk);
    k_wt<<<dim3(4, 16, 12), 256, 0, stream>>>(WQ, Wcat, HH, HD, 4, (size_t)QKVGW * HH, (size_t)HD * HH);
    k_wt<<<dim3(4, 16, 12), 256, 0, stream>>>(WK, Wcat + (size_t)512 * HH, HH, HD, 4, (size_t)QKVGW * HH, (size_t)HD * HH);
    k_wt<<<dim3(4, 16, 12), 256, 0, stream>>>(WV, Wcat + (size_t)1024 * HH, HH, HD, 4, (size_t)QKVGW * HH, (size_t)HD * HH);
    k_wt<<<dim3(16, 16, 3), 256, 0, stream>>>(WG, Wcat + (size_t)1536 * HH, HH, HH, 1, (size_t)QKVGW * HH, 0);
    k_wt<<<dim3(16, 16, 3), 256, 0, stream>>>(WO, WOt, HH, HH, 1, (size_t)HH * HH, 0);
    k_wt<<<dim3(64, 16, 3), 256, 0, stream>>>(fw1, F1t, HH, FFND, 1, (size_t)HH * FFND, 0);
    k_wt<<<dim3(16, 64, 3), 256, 0, stream>>>(fw2, F2t, FFND, HH, 1, (size_t)FFND * HH, 0);

    const float* curX = X0;
    for (int l = 0; l < NLAYERS; ++l) {
        const unsigned short* Bc = Wcat + (size_t)l * QKVGW * HH;
        const unsigned short* Bo = WOt + (size_t)l * HH * HH;
        const unsigned short* B1 = F1t + (size_t)l * HH * FFND;
        const unsigned short* B2 = F2t + (size_t)l * HH * FFND;
        k_ln<<<ROWS / 4, 256, 0, stream>>>(curX, l1w + l * HH, l1b + l * HH, Xn);
        dim3 gq(ROWS / 128, QKVGW / 128, 1);
        k_mm<0, 1><<<gq, 256, 0, stream>>>(Xn, Bc, QKVG, nullptr, nullptr, ROWS, QKVGW, HH, 0, 0, 0, nullptr);
        k_xpos<<<ROWS, 256, 0, stream>>>(QKVG, cq, sq, ck, sk);
        k_state<<<dim3(16, NHEADS, BB), 256, 0, stream>>>(QKVG, Bbuf);
        k_scan<<<dim3(4, NHEADS, BB), 256, 0, stream>>>(Bbuf, Abuf);
        k_ret2<<<dim3(16, NHEADS, BB), 256, 0, stream>>>(QKVG, Abuf, Yr);
        k_gate<<<ROWS, 256, 0, stream>>>(Yr, QKVG, gnw + l * HH, gnb + l * HH, Eb);
        dim3 g1(ROWS / 128, HH / 128, 1);
        k_mm<3, 0><<<g1, 256, 0, stream>>>(Eb, Bo, Y2, nullptr, curX, ROWS, HH, HH, 0, 0, 0, nullptr);
        k_ln<<<ROWS / 4, 256, 0, stream>>>(Y2, l2w + l * HH, l2b + l * HH, Xn);
        dim3 g2(ROWS / 128, FFND / 128, 1);
        k_mm<1, 1><<<g2, 256, 0, stream>>>(Xn, B1, Hb, fb1 + (size_t)l * FFND, nullptr, ROWS, FFND, HH, 0, 0, 0, nullptr);
        if (l == NLAYERS - 1) {
            k_mm<4, 0><<<g1, 256, 0, stream>>>(Hb, B2, outX, fb2 + (size_t)l * HH, Y2, ROWS, HH, FFND, 0, 0, 0, Xb);
        } else {
            k_mm<2, 0><<<g1, 256, 0, stream>>>(Hb, B2, Xbuf, fb2 + (size_t)l * HH, Y2, ROWS, HH, FFND, 0, 0, 0, nullptr);
        }
        curX = Xbuf;
    }
    dim3 g3(SS / 128, SS / 128, BB);
    k_mm<0, 0><<<g3, 256, 0, stream>>>(Xb, Xb, outG, nullptr, nullptr, SS, SS, HH,
                                       (size_t)SS * HH, (size_t)SS * HH, (size_t)SS * SS, nullptr);
}